// Round 10
// baseline (169.727 us; speedup 1.0000x reference)
//
#include <hip/hip_runtime.h>
#include <hip/hip_bf16.h>

#define N_NODES 100000
#define N_EDGES 1600000
#define DIM 128

#define NBIN 256          // row partitions
#define RPP  391          // rows per partition (391*256 = 100096 >= 100000)
#define PCAP 8192         // slab capacity per partition (mean 6250)
#define P1_BLOCKS 256
#define CHUNK (N_EDGES / P1_BLOCKS)   // 6250 edges per pass-1 block

typedef unsigned int uint_t;
typedef unsigned short ushort_t;
typedef float f32x4 __attribute__((ext_vector_type(4)));
typedef __bf16 bf16x8 __attribute__((ext_vector_type(8)));

// fp32 -> bf16 round-to-nearest-even
__device__ inline ushort_t f2bf(float f) {
    uint_t u = __float_as_uint(f);
    uint_t r = (u + 0x7FFFu + ((u >> 16) & 1u)) >> 16;
    return (ushort_t)r;
}
__device__ inline float bf2f(uint_t lo16) { return __uint_as_float(lo16 << 16); }

// ---------------- Pass 1: coarse bin into 256 partition slabs (coalesced writes) ---
// blocks 0..255: binning; blocks 256..319: WsumT16[m][k] = bf16(sum W[k][m])
__global__ __launch_bounds__(256) void pass1_bin(
        const int* __restrict__ rows, const int* __restrict__ cols,
        const float* __restrict__ vals, int* __restrict__ psize,
        long long* __restrict__ slab,
        const float* __restrict__ W0, const float* __restrict__ W1,
        const float* __restrict__ W2, ushort_t* __restrict__ WT) {
    if (blockIdx.x >= P1_BLOCKS) {
        int i = (blockIdx.x - P1_BLOCKS) * 256 + threadIdx.x;
        if (i < DIM * DIM) {
            int m = i & 127, k = i >> 7;
            float s = W0[k * DIM + m] + W1[k * DIM + m] + W2[k * DIM + m];
            WT[m * DIM + k] = f2bf(s);          // transposed bf16 (32 KB)
        }
        return;
    }
    __shared__ int hist[NBIN];
    __shared__ int binoff[NBIN];
    __shared__ int resv[NBIN];
    __shared__ int curs[NBIN];
    __shared__ long long ebuf[CHUNK];  // 50 KB
    __shared__ int edest[CHUNK];       // 25 KB

    int t = threadIdx.x;
    int e0 = blockIdx.x * CHUNK;

    if (t < NBIN) hist[t] = 0;
    __syncthreads();

    for (int i = t; i < CHUNK; i += 256) {
        int r = rows[e0 + i];
        atomicAdd(&hist[r / RPP], 1);
    }
    __syncthreads();

    if (t < 64) {
        int b = t * 4;
        int v0 = hist[b], v1 = hist[b + 1], v2 = hist[b + 2], v3 = hist[b + 3];
        int s = v0 + v1 + v2 + v3;
        int incl = s;
#pragma unroll
        for (int d = 1; d < 64; d <<= 1) {
            int o = __shfl_up(incl, d, 64);
            if (t >= d) incl += o;
        }
        int excl = incl - s;
        binoff[b]     = excl;
        binoff[b + 1] = excl + v0;
        binoff[b + 2] = excl + v0 + v1;
        binoff[b + 3] = excl + v0 + v1 + v2;
    }
    __syncthreads();

    if (t < NBIN) {
        int len = hist[t];
        int r = (len > 0) ? atomicAdd(&psize[t], len) : 0;
        resv[t] = t * PCAP + r;
        curs[t] = binoff[t];
    }
    __syncthreads();

    for (int i = t; i < CHUNK; i += 256) {
        int   r = rows[e0 + i];
        int   c = cols[e0 + i];
        float v = vals[e0 + i];
        int b  = r / RPP;
        int lr = r - b * RPP;
        int pos = atomicAdd(&curs[b], 1);
        uint_t key = ((uint_t)lr << 17) | (uint_t)c;
        ebuf[pos]  = ((long long)__float_as_int(v) << 32) | (long long)key;
        edest[pos] = resv[b] + (pos - binoff[b]);
    }
    __syncthreads();

    for (int i = t; i < CHUNK; i += 256)
        slab[edest[i]] = ebuf[i];
}

// ---------------- Pass 2: per-partition LDS counting sort, coalesced csr flush ----
// pscan is folded in: every block recomputes the 256-entry partition-base prefix.
__global__ __launch_bounds__(256) void pass2_sort(
        const long long* __restrict__ slab, const int* __restrict__ psize,
        int* __restrict__ off, long long* __restrict__ csr) {
    __shared__ int pb[NBIN + 1];
    __shared__ int cnt[RPP + 1];
    __shared__ int loff[RPP + 1];
    __shared__ int curs[RPP];
    __shared__ long long ebuf[PCAP];   // 64 KB

    int p = blockIdx.x, t = threadIdx.x;

    // inline pscan: wave 0, 4 partitions/lane
    if (t < 64) {
        int b = t * 4;
        int v0 = min(psize[b], PCAP),     v1 = min(psize[b + 1], PCAP);
        int v2 = min(psize[b + 2], PCAP), v3 = min(psize[b + 3], PCAP);
        int s = v0 + v1 + v2 + v3;
        int incl = s;
#pragma unroll
        for (int d = 1; d < 64; d <<= 1) {
            int o = __shfl_up(incl, d, 64);
            if (t >= d) incl += o;
        }
        int excl = incl - s;
        pb[b]     = excl;
        pb[b + 1] = excl + v0;
        pb[b + 2] = excl + v0 + v1;
        pb[b + 3] = excl + v0 + v1 + v2;
        if (t == 63) pb[NBIN] = incl;
    }
    for (int i = t; i < RPP + 1; i += 256) cnt[i] = 0;
    __syncthreads();

    int n = min(psize[p], PCAP);
    int base = pb[p];
    int rlo = p * RPP;
    int nrows = N_NODES - rlo; if (nrows > RPP) nrows = RPP;
    const long long* seg = slab + (long long)p * PCAP;

    if (p == NBIN - 1 && t == 0) off[N_NODES] = pb[NBIN];

    for (int i = t; i < n; i += 256) {
        uint_t key = (uint_t)(seg[i] & 0xFFFFFFFFll);
        atomicAdd(&cnt[key >> 17], 1);
    }
    __syncthreads();

    if (t < 64) {
        int b7 = t * 7;
        int v[7]; int s = 0;
#pragma unroll
        for (int k = 0; k < 7; ++k) {
            int idx = b7 + k;
            v[k] = (idx < RPP) ? cnt[idx] : 0;
            s += v[k];
        }
        int incl = s;
#pragma unroll
        for (int d = 1; d < 64; d <<= 1) {
            int o = __shfl_up(incl, d, 64);
            if (t >= d) incl += o;
        }
        int run = incl - s;
#pragma unroll
        for (int k = 0; k < 7; ++k) {
            int idx = b7 + k;
            if (idx < RPP) loff[idx] = run;
            run += v[k];
        }
    }
    __syncthreads();

    for (int i = t; i < nrows; i += 256) {
        curs[i] = loff[i];
        off[rlo + i] = base + loff[i];
    }
    __syncthreads();

    for (int i = t; i < n; i += 256) {
        long long ev = seg[i];
        uint_t key = (uint_t)(ev & 0xFFFFFFFFll);
        int lr = key >> 17;
        uint_t c = key & 0x1FFFFu;
        int pos = atomicAdd(&curs[lr], 1);
        ebuf[pos] = (long long)(((unsigned long long)ev & 0xFFFFFFFF00000000ull) | c);
    }
    __syncthreads();

    for (int i = t; i < n; i += 256)
        __builtin_nontemporal_store(ebuf[i], &csr[base + i]);
}

// ---------------- Gemm via MFMA: H(bf16) = x @ Wsum + one_hot_h -------------------
__global__ __launch_bounds__(256) void gemm_mfma(const float* __restrict__ x,
                                                 const float* __restrict__ oh,
                                                 const ushort_t* __restrict__ WT,
                                                 uint_t* __restrict__ H16) {
    int tid = threadIdx.x;
    int wv = tid >> 6, l = tid & 63;
    int lr = l & 15, kg = l >> 4;
    int hr = blockIdx.x * 64 + wv * 16 + lr;
    int hr_c = (hr < N_NODES) ? hr : (N_NODES - 1);

    f32x4 acc[8] = {};
    const float* xrow = x + (size_t)hr_c * DIM;

#pragma unroll
    for (int s = 0; s < 4; ++s) {
        f32x4 xa = __builtin_nontemporal_load((const f32x4*)(xrow + s * 32 + kg * 8));
        f32x4 xb = __builtin_nontemporal_load((const f32x4*)(xrow + s * 32 + kg * 8 + 4));
        union { bf16x8 v; __bf16 h[8]; } b;
        b.h[0] = (__bf16)xa.x; b.h[1] = (__bf16)xa.y;
        b.h[2] = (__bf16)xa.z; b.h[3] = (__bf16)xa.w;
        b.h[4] = (__bf16)xb.x; b.h[5] = (__bf16)xb.y;
        b.h[6] = (__bf16)xb.z; b.h[7] = (__bf16)xb.w;
#pragma unroll
        for (int mt = 0; mt < 8; ++mt) {
            bf16x8 a = *(const bf16x8*)&WT[(mt * 16 + lr) * DIM + s * 32 + kg * 8];
            acc[mt] = __builtin_amdgcn_mfma_f32_16x16x32_bf16(a, b.v, acc[mt], 0, 0, 0);
        }
    }

    if (hr < N_NODES) {
#pragma unroll
        for (int mt = 0; mt < 8; ++mt) {
            int c0 = mt * 16 + kg * 4;
            f32x4 o = __builtin_nontemporal_load((const f32x4*)&oh[(size_t)hr * DIM + c0]);
            float f0 = acc[mt].x + o.x, f1 = acc[mt].y + o.y;
            float f2 = acc[mt].z + o.z, f3 = acc[mt].w + o.w;
            uint2 pk;
            pk.x = (uint_t)f2bf(f0) | ((uint_t)f2bf(f1) << 16);
            pk.y = (uint_t)f2bf(f2) | ((uint_t)f2bf(f3) << 16);
            *(uint2*)&H16[(size_t)hr * (DIM / 2) + c0 / 2] = pk;
        }
    }
}

// ---------------- Gather: 4 rows/wave, 16 lanes/row, 8-deep MLP, 2 acc banks ------
__global__ __launch_bounds__(256) void gather_kernel(const uint_t* __restrict__ H16,
                                                     const int* __restrict__ off,
                                                     const long long* __restrict__ csr,
                                                     float* __restrict__ out) {
    int tid  = threadIdx.x;
    int wave = tid >> 6;
    int lane = tid & 63;
    int grp  = lane >> 4;
    int il   = lane & 15;
    int wid  = blockIdx.x * 16 + wave * 4 + grp;

    int s = off[wid], e = off[wid + 1];
    float acc0[8] = {}, acc1[8] = {};

#define ACC8(A, h, v)                                                      \
        A[0] += (v) * bf2f((h).x & 0xFFFFu); A[1] += (v) * bf2f((h).x >> 16); \
        A[2] += (v) * bf2f((h).y & 0xFFFFu); A[3] += (v) * bf2f((h).y >> 16); \
        A[4] += (v) * bf2f((h).z & 0xFFFFu); A[5] += (v) * bf2f((h).z >> 16); \
        A[6] += (v) * bf2f((h).w & 0xFFFFu); A[7] += (v) * bf2f((h).w >> 16);

    int p = s;
    // 8-deep main loop: all csr loads, then all H16 loads, then FMAs (2 banks)
    for (; p + 7 < e; p += 8) {
        long long cv[8];
#pragma unroll
        for (int k = 0; k < 8; ++k)
            cv[k] = __builtin_nontemporal_load(&csr[p + k]);
        uint4 h[8];
#pragma unroll
        for (int k = 0; k < 8; ++k)
            h[k] = *(const uint4*)&H16[(long long)(int)(cv[k] & 0x1FFFF) * (DIM / 2) + il * 4];
#pragma unroll
        for (int k = 0; k < 8; k += 2) {
            float va = __int_as_float((int)(cv[k] >> 32));
            float vb = __int_as_float((int)(cv[k + 1] >> 32));
            ACC8(acc0, h[k], va)
            ACC8(acc1, h[k + 1], vb)
        }
    }
    // 4-deep tail
    for (; p + 3 < e; p += 4) {
        long long cv[4];
#pragma unroll
        for (int k = 0; k < 4; ++k)
            cv[k] = __builtin_nontemporal_load(&csr[p + k]);
        uint4 h[4];
#pragma unroll
        for (int k = 0; k < 4; ++k)
            h[k] = *(const uint4*)&H16[(long long)(int)(cv[k] & 0x1FFFF) * (DIM / 2) + il * 4];
#pragma unroll
        for (int k = 0; k < 4; k += 2) {
            float va = __int_as_float((int)(cv[k] >> 32));
            float vb = __int_as_float((int)(cv[k + 1] >> 32));
            ACC8(acc0, h[k], va)
            ACC8(acc1, h[k + 1], vb)
        }
    }
    // scalar tail
    for (; p < e; ++p) {
        long long cv = __builtin_nontemporal_load(&csr[p]);
        float v = __int_as_float((int)(cv >> 32));
        uint4 h = *(const uint4*)&H16[(long long)(int)(cv & 0x1FFFF) * (DIM / 2) + il * 4];
        ACC8(acc0, h, v)
    }
#undef ACC8

    float* op = &out[(long long)wid * DIM + il * 8];
    f32x4 o0 = {acc0[0] + acc1[0], acc0[1] + acc1[1], acc0[2] + acc1[2], acc0[3] + acc1[3]};
    f32x4 o1 = {acc0[4] + acc1[4], acc0[5] + acc1[5], acc0[6] + acc1[6], acc0[7] + acc1[7]};
    __builtin_nontemporal_store(o0, (f32x4*)op);
    __builtin_nontemporal_store(o1, (f32x4*)(op + 4));
}

extern "C" void kernel_launch(void* const* d_in, const int* in_sizes, int n_in,
                              void* d_out, int out_size, void* d_ws, size_t ws_size,
                              hipStream_t stream) {
    const float* x    = (const float*)d_in[0];
    const float* oh   = (const float*)d_in[1];
    const float* W0   = (const float*)d_in[2];
    const float* W1   = (const float*)d_in[3];
    const float* W2   = (const float*)d_in[4];
    const int*   rows = (const int*)d_in[5];
    const int*   cols = (const int*)d_in[6];
    const float* vals = (const float*)d_in[7];
    float* out = (float*)d_out;

    // workspace layout
    char* p = (char*)d_ws;
    size_t oW    = 0;                                   // WsumT bf16: 32 KB (64 KB reserved)
    size_t oH    = oW + 64 * 1024;                      // H bf16: 25.6 MB
    size_t oOff  = oH + (size_t)N_NODES * DIM * 2;      // off: N_NODES+1 (+pad)
    size_t oPs   = oOff + (size_t)(N_NODES + 32) * 4;   // psize: 256 ints
    size_t oSlab = oPs + 4096;                          // slabs: 256*8192*8B = 16.8 MB
    size_t oCsr  = oSlab + (size_t)NBIN * PCAP * 8;     // csr: 12.8 MB

    ushort_t*  WT    = (ushort_t*)(p + oW);
    uint_t*    H16   = (uint_t*)(p + oH);
    int*       off   = (int*)(p + oOff);
    int*       psize = (int*)(p + oPs);
    long long* slab  = (long long*)(p + oSlab);
    long long* csr   = (long long*)(p + oCsr);

    (void)hipMemsetAsync(psize, 0, NBIN * sizeof(int), stream);
    pass1_bin<<<P1_BLOCKS + 64, 256, 0, stream>>>(rows, cols, vals, psize, slab,
                                                  W0, W1, W2, WT);
    pass2_sort<<<NBIN, 256, 0, stream>>>(slab, psize, off, csr);
    gemm_mfma<<<(N_NODES + 63) / 64, 256, 0, stream>>>(x, oh, WT, H16);
    gather_kernel<<<N_NODES / 16, 256, 0, stream>>>(H16, off, csr, out);
}

// Round 11
// 162.933 us; speedup vs baseline: 1.0417x; 1.0417x over previous
//
#include <hip/hip_runtime.h>
#include <hip/hip_bf16.h>

#define N_NODES 100000
#define N_EDGES 1600000
#define DIM 128

#define NBIN 256          // row partitions
#define RPP  391          // rows per partition (391*256 = 100096 >= 100000)
#define PCAP 8192         // slab capacity per partition (mean 6250)
#define P1_BLOCKS 512
#define CHUNK (N_EDGES / P1_BLOCKS)   // 3125 edges per pass-1 block

typedef unsigned int uint_t;
typedef unsigned short ushort_t;
typedef float f32x4 __attribute__((ext_vector_type(4)));
typedef __bf16 bf16x8 __attribute__((ext_vector_type(8)));

// fp32 -> bf16 round-to-nearest-even
__device__ inline uint_t f2bf(float f) {
    uint_t u = __float_as_uint(f);
    return (u + 0x7FFFu + ((u >> 16) & 1u)) >> 16;
}
__device__ inline float bf2f(uint_t lo16) { return __uint_as_float(lo16 << 16); }

// ---------------- Pass 1: coarse bin into 256 partition slabs (coalesced writes) ---
// blocks 0..511: binning; blocks 512..575: WsumT16[m][k] = bf16(sum W[k][m])
__global__ __launch_bounds__(256) void pass1_bin(
        const int* __restrict__ rows, const int* __restrict__ cols,
        const float* __restrict__ vals, int* __restrict__ psize,
        long long* __restrict__ slab,
        const float* __restrict__ W0, const float* __restrict__ W1,
        const float* __restrict__ W2, ushort_t* __restrict__ WT) {
    if (blockIdx.x >= P1_BLOCKS) {
        int i = (blockIdx.x - P1_BLOCKS) * 256 + threadIdx.x;
        if (i < DIM * DIM) {
            int m = i & 127, k = i >> 7;
            float s = W0[k * DIM + m] + W1[k * DIM + m] + W2[k * DIM + m];
            WT[m * DIM + k] = (ushort_t)f2bf(s);   // transposed bf16 (32 KB)
        }
        return;
    }
    __shared__ int hist[NBIN];
    __shared__ int binoff[NBIN];
    __shared__ int resv[NBIN];
    __shared__ int curs[NBIN];
    __shared__ long long ebuf[CHUNK];  // 25 KB
    __shared__ int edest[CHUNK];       // 12.5 KB

    int t = threadIdx.x;
    int e0 = blockIdx.x * CHUNK;

    if (t < NBIN) hist[t] = 0;
    __syncthreads();

    for (int i = t; i < CHUNK; i += 256) {
        int r = rows[e0 + i];
        atomicAdd(&hist[r / RPP], 1);
    }
    __syncthreads();

    if (t < 64) {
        int b = t * 4;
        int v0 = hist[b], v1 = hist[b + 1], v2 = hist[b + 2], v3 = hist[b + 3];
        int s = v0 + v1 + v2 + v3;
        int incl = s;
#pragma unroll
        for (int d = 1; d < 64; d <<= 1) {
            int o = __shfl_up(incl, d, 64);
            if (t >= d) incl += o;
        }
        int excl = incl - s;
        binoff[b]     = excl;
        binoff[b + 1] = excl + v0;
        binoff[b + 2] = excl + v0 + v1;
        binoff[b + 3] = excl + v0 + v1 + v2;
    }
    __syncthreads();

    if (t < NBIN) {
        int len = hist[t];
        int r = (len > 0) ? atomicAdd(&psize[t], len) : 0;
        resv[t] = t * PCAP + r;
        curs[t] = binoff[t];
    }
    __syncthreads();

    for (int i = t; i < CHUNK; i += 256) {
        int   r = rows[e0 + i];
        int   c = cols[e0 + i];
        float v = vals[e0 + i];
        int b  = r / RPP;
        int lr = r - b * RPP;
        int pos = atomicAdd(&curs[b], 1);
        uint_t key = ((uint_t)lr << 17) | (uint_t)c;
        ebuf[pos]  = ((long long)__float_as_int(v) << 32) | (long long)key;
        edest[pos] = resv[b] + (pos - binoff[b]);
    }
    __syncthreads();

    for (int i = t; i < CHUNK; i += 256)
        slab[edest[i]] = ebuf[i];
}

// ---------------- Pass 2: per-partition LDS counting sort, coalesced csr flush ----
// pscan folded in: every block recomputes the 256-entry partition-base prefix.
__global__ __launch_bounds__(256) void pass2_sort(
        const long long* __restrict__ slab, const int* __restrict__ psize,
        int* __restrict__ off, long long* __restrict__ csr) {
    __shared__ int pb[NBIN + 1];
    __shared__ int cnt[RPP + 1];
    __shared__ int loff[RPP + 1];
    __shared__ int curs[RPP];
    __shared__ long long ebuf[PCAP];   // 64 KB

    int p = blockIdx.x, t = threadIdx.x;

    if (t < 64) {
        int b = t * 4;
        int v0 = min(psize[b], PCAP),     v1 = min(psize[b + 1], PCAP);
        int v2 = min(psize[b + 2], PCAP), v3 = min(psize[b + 3], PCAP);
        int s = v0 + v1 + v2 + v3;
        int incl = s;
#pragma unroll
        for (int d = 1; d < 64; d <<= 1) {
            int o = __shfl_up(incl, d, 64);
            if (t >= d) incl += o;
        }
        int excl = incl - s;
        pb[b]     = excl;
        pb[b + 1] = excl + v0;
        pb[b + 2] = excl + v0 + v1;
        pb[b + 3] = excl + v0 + v1 + v2;
        if (t == 63) pb[NBIN] = incl;
    }
    for (int i = t; i < RPP + 1; i += 256) cnt[i] = 0;
    __syncthreads();

    int n = min(psize[p], PCAP);
    int base = pb[p];
    int rlo = p * RPP;
    int nrows = N_NODES - rlo; if (nrows > RPP) nrows = RPP;
    const long long* seg = slab + (long long)p * PCAP;

    if (p == NBIN - 1 && t == 0) off[N_NODES] = pb[NBIN];

    for (int i = t; i < n; i += 256) {
        uint_t key = (uint_t)(seg[i] & 0xFFFFFFFFll);
        atomicAdd(&cnt[key >> 17], 1);
    }
    __syncthreads();

    if (t < 64) {
        int b7 = t * 7;
        int v[7]; int s = 0;
#pragma unroll
        for (int k = 0; k < 7; ++k) {
            int idx = b7 + k;
            v[k] = (idx < RPP) ? cnt[idx] : 0;
            s += v[k];
        }
        int incl = s;
#pragma unroll
        for (int d = 1; d < 64; d <<= 1) {
            int o = __shfl_up(incl, d, 64);
            if (t >= d) incl += o;
        }
        int run = incl - s;
#pragma unroll
        for (int k = 0; k < 7; ++k) {
            int idx = b7 + k;
            if (idx < RPP) loff[idx] = run;
            run += v[k];
        }
    }
    __syncthreads();

    for (int i = t; i < nrows; i += 256) {
        curs[i] = loff[i];
        off[rlo + i] = base + loff[i];
    }
    __syncthreads();

    for (int i = t; i < n; i += 256) {
        long long ev = seg[i];
        uint_t key = (uint_t)(ev & 0xFFFFFFFFll);
        int lr = key >> 17;
        uint_t c = key & 0x1FFFFu;
        int pos = atomicAdd(&curs[lr], 1);
        ebuf[pos] = (long long)(((unsigned long long)ev & 0xFFFFFFFF00000000ull) | c);
    }
    __syncthreads();

    for (int i = t; i < n; i += 256)
        __builtin_nontemporal_store(ebuf[i], &csr[base + i]);
}

// ---------------- Gemm via MFMA, LDS-staged coalesced loads -----------------------
// Stage 64 x-rows coalesced -> bf16 LDS tile (stride 136 bf16: 16B-aligned b128
// reads, 2-way bank aliasing = free). MFMA fragment math identical to the verified
// round-9 kernel; only the B/oh data path changed (global-strided -> LDS).
#define GROWS 64
#define XSTR 136   // bf16 per row (128 + 8 pad); row stride 272 B
__global__ __launch_bounds__(256) void gemm_mfma(const float* __restrict__ x,
                                                 const float* __restrict__ oh,
                                                 const ushort_t* __restrict__ WT,
                                                 uint_t* __restrict__ H16) {
    __shared__ ushort_t xs[GROWS * XSTR];   // 17408 B
    int tid = threadIdx.x;
    int wv = tid >> 6, l = tid & 63;
    int lr = l & 15, kg = l >> 4;
    int lrow = wv * 16 + lr;
    long long base_row = (long long)blockIdx.x * GROWS;
    long long hr = base_row + lrow;

    // stage x: 64 rows * 32 float4, 8 per thread, coalesced NT loads
    const f32x4* xg = (const f32x4*)x;
#pragma unroll
    for (int i = 0; i < 8; ++i) {
        int g = tid + i * 256;
        int row = g >> 5, c4 = g & 31;
        long long sr = base_row + row; if (sr >= N_NODES) sr = N_NODES - 1;
        f32x4 v = __builtin_nontemporal_load(xg + sr * 32 + c4);
        ushort_t* d = &xs[row * XSTR + c4 * 4];
        d[0] = (ushort_t)f2bf(v.x); d[1] = (ushort_t)f2bf(v.y);
        d[2] = (ushort_t)f2bf(v.z); d[3] = (ushort_t)f2bf(v.w);
    }
    __syncthreads();

    f32x4 acc[8] = {};
#pragma unroll
    for (int s = 0; s < 4; ++s) {
        bf16x8 b = *(const bf16x8*)&xs[lrow * XSTR + s * 32 + kg * 8];
#pragma unroll
        for (int mt = 0; mt < 8; ++mt) {
            bf16x8 a = *(const bf16x8*)&WT[(mt * 16 + lr) * DIM + s * 32 + kg * 8];
            acc[mt] = __builtin_amdgcn_mfma_f32_16x16x32_bf16(a, b, acc[mt], 0, 0, 0);
        }
    }
    __syncthreads();

    // stage oh (bf16, same buffer/pattern)
    const f32x4* og = (const f32x4*)oh;
#pragma unroll
    for (int i = 0; i < 8; ++i) {
        int g = tid + i * 256;
        int row = g >> 5, c4 = g & 31;
        long long sr = base_row + row; if (sr >= N_NODES) sr = N_NODES - 1;
        f32x4 v = __builtin_nontemporal_load(og + sr * 32 + c4);
        ushort_t* d = &xs[row * XSTR + c4 * 4];
        d[0] = (ushort_t)f2bf(v.x); d[1] = (ushort_t)f2bf(v.y);
        d[2] = (ushort_t)f2bf(v.z); d[3] = (ushort_t)f2bf(v.w);
    }
    __syncthreads();

    if (hr < N_NODES) {
#pragma unroll
        for (int mt = 0; mt < 8; ++mt) {
            int c0 = mt * 16 + kg * 4;
            const uint_t* ow = (const uint_t*)&xs[lrow * XSTR + c0];
            uint_t w0 = ow[0], w1 = ow[1];
            float f0 = acc[mt].x + bf2f(w0 & 0xFFFFu);
            float f1 = acc[mt].y + bf2f(w0 >> 16);
            float f2 = acc[mt].z + bf2f(w1 & 0xFFFFu);
            float f3 = acc[mt].w + bf2f(w1 >> 16);
            uint2 pk;
            pk.x = f2bf(f0) | (f2bf(f1) << 16);
            pk.y = f2bf(f2) | (f2bf(f3) << 16);
            *(uint2*)&H16[(size_t)hr * (DIM / 2) + c0 / 2] = pk;
        }
    }
}

// ---------------- Gather: 4 rows/wave, 16 lanes/row, 4-deep MLP (round-9) ---------
__global__ __launch_bounds__(256) void gather_kernel(const uint_t* __restrict__ H16,
                                                     const int* __restrict__ off,
                                                     const long long* __restrict__ csr,
                                                     float* __restrict__ out) {
    int tid  = threadIdx.x;
    int wave = tid >> 6;
    int lane = tid & 63;
    int grp  = lane >> 4;
    int il   = lane & 15;
    int wid  = blockIdx.x * 16 + wave * 4 + grp;

    int s = off[wid], e = off[wid + 1];
    float acc[8] = {};

#define ACC8(h, v)                                                            \
    acc[0] += (v) * bf2f((h).x & 0xFFFFu); acc[1] += (v) * bf2f((h).x >> 16); \
    acc[2] += (v) * bf2f((h).y & 0xFFFFu); acc[3] += (v) * bf2f((h).y >> 16); \
    acc[4] += (v) * bf2f((h).z & 0xFFFFu); acc[5] += (v) * bf2f((h).z >> 16); \
    acc[6] += (v) * bf2f((h).w & 0xFFFFu); acc[7] += (v) * bf2f((h).w >> 16);

    int p = s;
    for (; p + 3 < e; p += 4) {
        long long cv0 = __builtin_nontemporal_load(&csr[p]);
        long long cv1 = __builtin_nontemporal_load(&csr[p + 1]);
        long long cv2 = __builtin_nontemporal_load(&csr[p + 2]);
        long long cv3 = __builtin_nontemporal_load(&csr[p + 3]);
        uint4 h0 = *(const uint4*)&H16[(long long)(int)(cv0 & 0x1FFFF) * (DIM / 2) + il * 4];
        uint4 h1 = *(const uint4*)&H16[(long long)(int)(cv1 & 0x1FFFF) * (DIM / 2) + il * 4];
        uint4 h2 = *(const uint4*)&H16[(long long)(int)(cv2 & 0x1FFFF) * (DIM / 2) + il * 4];
        uint4 h3 = *(const uint4*)&H16[(long long)(int)(cv3 & 0x1FFFF) * (DIM / 2) + il * 4];
        float v0 = __int_as_float((int)(cv0 >> 32));
        float v1 = __int_as_float((int)(cv1 >> 32));
        float v2 = __int_as_float((int)(cv2 >> 32));
        float v3 = __int_as_float((int)(cv3 >> 32));
        ACC8(h0, v0) ACC8(h1, v1) ACC8(h2, v2) ACC8(h3, v3)
    }
    for (; p < e; ++p) {
        long long cv = __builtin_nontemporal_load(&csr[p]);
        float v = __int_as_float((int)(cv >> 32));
        uint4 h = *(const uint4*)&H16[(long long)(int)(cv & 0x1FFFF) * (DIM / 2) + il * 4];
        ACC8(h, v)
    }
#undef ACC8

    float* op = &out[(long long)wid * DIM + il * 8];
    f32x4 o0 = {acc[0], acc[1], acc[2], acc[3]};
    f32x4 o1 = {acc[4], acc[5], acc[6], acc[7]};
    __builtin_nontemporal_store(o0, (f32x4*)op);
    __builtin_nontemporal_store(o1, (f32x4*)(op + 4));
}

extern "C" void kernel_launch(void* const* d_in, const int* in_sizes, int n_in,
                              void* d_out, int out_size, void* d_ws, size_t ws_size,
                              hipStream_t stream) {
    const float* x    = (const float*)d_in[0];
    const float* oh   = (const float*)d_in[1];
    const float* W0   = (const float*)d_in[2];
    const float* W1   = (const float*)d_in[3];
    const float* W2   = (const float*)d_in[4];
    const int*   rows = (const int*)d_in[5];
    const int*   cols = (const int*)d_in[6];
    const float* vals = (const float*)d_in[7];
    float* out = (float*)d_out;

    // workspace layout
    char* p = (char*)d_ws;
    size_t oW    = 0;                                   // WsumT bf16: 32 KB (64 KB reserved)
    size_t oH    = oW + 64 * 1024;                      // H bf16: 25.6 MB
    size_t oOff  = oH + (size_t)N_NODES * DIM * 2;      // off: N_NODES+1 (+pad)
    size_t oPs   = oOff + (size_t)(N_NODES + 32) * 4;   // psize: 256 ints
    size_t oSlab = oPs + 4096;                          // slabs: 256*8192*8B = 16.8 MB
    size_t oCsr  = oSlab + (size_t)NBIN * PCAP * 8;     // csr: 12.8 MB

    ushort_t*  WT    = (ushort_t*)(p + oW);
    uint_t*    H16   = (uint_t*)(p + oH);
    int*       off   = (int*)(p + oOff);
    int*       psize = (int*)(p + oPs);
    long long* slab  = (long long*)(p + oSlab);
    long long* csr   = (long long*)(p + oCsr);

    (void)hipMemsetAsync(psize, 0, NBIN * sizeof(int), stream);
    pass1_bin<<<P1_BLOCKS + 64, 256, 0, stream>>>(rows, cols, vals, psize, slab,
                                                  W0, W1, W2, WT);
    pass2_sort<<<NBIN, 256, 0, stream>>>(slab, psize, off, csr);
    gemm_mfma<<<(N_NODES + GROWS - 1) / GROWS, 256, 0, stream>>>(x, oh, WT, H16);
    gather_kernel<<<N_NODES / 16, 256, 0, stream>>>(H16, off, csr, out);
}

// Round 12
// 161.851 us; speedup vs baseline: 1.0487x; 1.0067x over previous
//
#include <hip/hip_runtime.h>
#include <hip/hip_bf16.h>

#define N_NODES 100000
#define N_EDGES 1600000
#define DIM 128

#define NBIN 512          // row partitions
#define RPP  196          // rows per partition (196*511 >= 100000)
#define PCAP 4096         // slab capacity per partition (mean 3125, +17 sigma)
#define P1_BLOCKS 512
#define CHUNK (N_EDGES / P1_BLOCKS)   // 3125 edges per pass-1 block

typedef unsigned int uint_t;
typedef unsigned short ushort_t;
typedef float f32x4 __attribute__((ext_vector_type(4)));
typedef __bf16 bf16x8 __attribute__((ext_vector_type(8)));

// fp32 -> bf16 round-to-nearest-even
__device__ inline uint_t f2bf(float f) {
    uint_t u = __float_as_uint(f);
    return (u + 0x7FFFu + ((u >> 16) & 1u)) >> 16;
}
__device__ inline float bf2f(uint_t lo16) { return __uint_as_float(lo16 << 16); }

// ---------------- Pass 1: coarse bin into 512 partition slabs (coalesced writes) ---
// blocks 0..511: binning; blocks 512..575: WsumT16[m][k] = bf16(sum W[k][m])
__global__ __launch_bounds__(256) void pass1_bin(
        const int* __restrict__ rows, const int* __restrict__ cols,
        const float* __restrict__ vals, int* __restrict__ psize,
        long long* __restrict__ slab,
        const float* __restrict__ W0, const float* __restrict__ W1,
        const float* __restrict__ W2, ushort_t* __restrict__ WT) {
    if (blockIdx.x >= P1_BLOCKS) {
        int i = (blockIdx.x - P1_BLOCKS) * 256 + threadIdx.x;
        if (i < DIM * DIM) {
            int m = i & 127, k = i >> 7;
            float s = W0[k * DIM + m] + W1[k * DIM + m] + W2[k * DIM + m];
            WT[m * DIM + k] = (ushort_t)f2bf(s);   // transposed bf16 (32 KB)
        }
        return;
    }
    __shared__ int hist[NBIN];       // 2 KB
    __shared__ int binoff[NBIN];     // 2 KB
    __shared__ int resv[NBIN];       // 2 KB
    __shared__ int curs[NBIN];       // 2 KB
    __shared__ long long ebuf[CHUNK];  // 25 KB
    __shared__ int edest[CHUNK];       // 12.5 KB

    int t = threadIdx.x;
    int e0 = blockIdx.x * CHUNK;

    for (int i = t; i < NBIN; i += 256) hist[i] = 0;
    __syncthreads();

    for (int i = t; i < CHUNK; i += 256) {
        int r = rows[e0 + i];
        atomicAdd(&hist[r / RPP], 1);
    }
    __syncthreads();

    // exclusive scan of 512 bins: wave 0, 8 bins/lane
    if (t < 64) {
        int b = t * 8;
        int v[8]; int s = 0;
#pragma unroll
        for (int k = 0; k < 8; ++k) { v[k] = hist[b + k]; s += v[k]; }
        int incl = s;
#pragma unroll
        for (int d = 1; d < 64; d <<= 1) {
            int o = __shfl_up(incl, d, 64);
            if (t >= d) incl += o;
        }
        int run = incl - s;
#pragma unroll
        for (int k = 0; k < 8; ++k) { binoff[b + k] = run; run += v[k]; }
    }
    __syncthreads();

    for (int i = t; i < NBIN; i += 256) {
        int len = hist[i];
        int r = (len > 0) ? atomicAdd(&psize[i], len) : 0;
        resv[i] = i * PCAP + r;
        curs[i] = binoff[i];
    }
    __syncthreads();

    for (int i = t; i < CHUNK; i += 256) {
        int   r = rows[e0 + i];
        int   c = cols[e0 + i];
        float v = vals[e0 + i];
        int b  = r / RPP;
        int lr = r - b * RPP;
        int pos = atomicAdd(&curs[b], 1);
        uint_t key = ((uint_t)lr << 17) | (uint_t)c;   // lr<256 (8b), c<2^17
        ebuf[pos]  = ((long long)__float_as_int(v) << 32) | (long long)key;
        edest[pos] = resv[b] + (pos - binoff[b]);
    }
    __syncthreads();

    // flush: contiguous ~6-entry runs per bin
    for (int i = t; i < CHUNK; i += 256)
        slab[edest[i]] = ebuf[i];
}

// ---------------- Pass 2: per-partition LDS counting sort ------------------------
// pscan folded in; slab segment read ONCE into LDS; scatter writes go directly to
// the partition's contiguous ~32KB csr window (L2-hot, flushed once).
__global__ __launch_bounds__(256) void pass2_sort(
        const long long* __restrict__ slab, const int* __restrict__ psize,
        int* __restrict__ off, long long* __restrict__ csr) {
    __shared__ int pb[NBIN + 1];       // 2 KB
    __shared__ int cnt[RPP + 1];
    __shared__ int loff[RPP + 1];
    __shared__ int curs[RPP];
    __shared__ long long ebuf[PCAP];   // 32 KB

    int p = blockIdx.x, t = threadIdx.x;

    // inline pscan over 512 partitions: wave 0, 8/lane
    if (t < 64) {
        int b = t * 8;
        int v[8]; int s = 0;
#pragma unroll
        for (int k = 0; k < 8; ++k) { v[k] = min(psize[b + k], PCAP); s += v[k]; }
        int incl = s;
#pragma unroll
        for (int d = 1; d < 64; d <<= 1) {
            int o = __shfl_up(incl, d, 64);
            if (t >= d) incl += o;
        }
        int run = incl - s;
#pragma unroll
        for (int k = 0; k < 8; ++k) { pb[b + k] = run; run += v[k]; }
        if (t == 63) pb[NBIN] = incl;
    }
    for (int i = t; i < RPP + 1; i += 256) cnt[i] = 0;
    __syncthreads();

    int n = min(psize[p], PCAP);
    int base = pb[p];
    int rlo = p * RPP;
    int nrows = N_NODES - rlo;
    if (nrows > RPP) nrows = RPP;
    if (nrows < 0) nrows = 0;
    const long long* seg = slab + (long long)p * PCAP;

    if (p == NBIN - 1 && t == 0) off[N_NODES] = pb[NBIN];

    // single coalesced read of the segment -> LDS; hist on the fly
    for (int i = t; i < n; i += 256) {
        long long ev = __builtin_nontemporal_load(&seg[i]);
        ebuf[i] = ev;
        uint_t key = (uint_t)(ev & 0xFFFFFFFFll);
        atomicAdd(&cnt[key >> 17], 1);
    }
    __syncthreads();

    // exclusive scan of RPP=196 counts: wave 0, 4/lane (64*4=256)
    if (t < 64) {
        int b4 = t * 4;
        int v[4]; int s = 0;
#pragma unroll
        for (int k = 0; k < 4; ++k) {
            int idx = b4 + k;
            v[k] = (idx < RPP) ? cnt[idx] : 0;
            s += v[k];
        }
        int incl = s;
#pragma unroll
        for (int d = 1; d < 64; d <<= 1) {
            int o = __shfl_up(incl, d, 64);
            if (t >= d) incl += o;
        }
        int run = incl - s;
#pragma unroll
        for (int k = 0; k < 4; ++k) {
            int idx = b4 + k;
            if (idx < RPP) loff[idx] = run;
            run += v[k];
        }
    }
    __syncthreads();

    for (int i = t; i < nrows; i += 256) {
        curs[i] = loff[i];
        off[rlo + i] = base + loff[i];
    }
    __syncthreads();

    // scatter LDS -> global csr (random within ~32KB L2-hot window)
    for (int i = t; i < n; i += 256) {
        long long ev = ebuf[i];
        uint_t key = (uint_t)(ev & 0xFFFFFFFFll);
        int lr = key >> 17;
        uint_t c = key & 0x1FFFFu;
        int pos = atomicAdd(&curs[lr], 1);
        csr[base + pos] = (long long)(((unsigned long long)ev & 0xFFFFFFFF00000000ull) | c);
    }
}

// ---------------- Gemm via MFMA, LDS-staged coalesced loads (round-11) ------------
#define GROWS 64
#define XSTR 136   // bf16 per row (128 + 8 pad)
__global__ __launch_bounds__(256) void gemm_mfma(const float* __restrict__ x,
                                                 const float* __restrict__ oh,
                                                 const ushort_t* __restrict__ WT,
                                                 uint_t* __restrict__ H16) {
    __shared__ ushort_t xs[GROWS * XSTR];   // 17408 B
    int tid = threadIdx.x;
    int wv = tid >> 6, l = tid & 63;
    int lr = l & 15, kg = l >> 4;
    int lrow = wv * 16 + lr;
    long long base_row = (long long)blockIdx.x * GROWS;
    long long hr = base_row + lrow;

    const f32x4* xg = (const f32x4*)x;
#pragma unroll
    for (int i = 0; i < 8; ++i) {
        int g = tid + i * 256;
        int row = g >> 5, c4 = g & 31;
        long long sr = base_row + row; if (sr >= N_NODES) sr = N_NODES - 1;
        f32x4 v = __builtin_nontemporal_load(xg + sr * 32 + c4);
        ushort_t* d = &xs[row * XSTR + c4 * 4];
        d[0] = (ushort_t)f2bf(v.x); d[1] = (ushort_t)f2bf(v.y);
        d[2] = (ushort_t)f2bf(v.z); d[3] = (ushort_t)f2bf(v.w);
    }
    __syncthreads();

    f32x4 acc[8] = {};
#pragma unroll
    for (int s = 0; s < 4; ++s) {
        bf16x8 b = *(const bf16x8*)&xs[lrow * XSTR + s * 32 + kg * 8];
#pragma unroll
        for (int mt = 0; mt < 8; ++mt) {
            bf16x8 a = *(const bf16x8*)&WT[(mt * 16 + lr) * DIM + s * 32 + kg * 8];
            acc[mt] = __builtin_amdgcn_mfma_f32_16x16x32_bf16(a, b, acc[mt], 0, 0, 0);
        }
    }
    __syncthreads();

    const f32x4* og = (const f32x4*)oh;
#pragma unroll
    for (int i = 0; i < 8; ++i) {
        int g = tid + i * 256;
        int row = g >> 5, c4 = g & 31;
        long long sr = base_row + row; if (sr >= N_NODES) sr = N_NODES - 1;
        f32x4 v = __builtin_nontemporal_load(og + sr * 32 + c4);
        ushort_t* d = &xs[row * XSTR + c4 * 4];
        d[0] = (ushort_t)f2bf(v.x); d[1] = (ushort_t)f2bf(v.y);
        d[2] = (ushort_t)f2bf(v.z); d[3] = (ushort_t)f2bf(v.w);
    }
    __syncthreads();

    if (hr < N_NODES) {
#pragma unroll
        for (int mt = 0; mt < 8; ++mt) {
            int c0 = mt * 16 + kg * 4;
            const uint_t* ow = (const uint_t*)&xs[lrow * XSTR + c0];
            uint_t w0 = ow[0], w1 = ow[1];
            float f0 = acc[mt].x + bf2f(w0 & 0xFFFFu);
            float f1 = acc[mt].y + bf2f(w0 >> 16);
            float f2 = acc[mt].z + bf2f(w1 & 0xFFFFu);
            float f3 = acc[mt].w + bf2f(w1 >> 16);
            uint2 pk;
            pk.x = f2bf(f0) | (f2bf(f1) << 16);
            pk.y = f2bf(f2) | (f2bf(f3) << 16);
            *(uint2*)&H16[(size_t)hr * (DIM / 2) + c0 / 2] = pk;
        }
    }
}

// ---------------- Gather: 4 rows/wave, 16 lanes/row, 4-deep MLP (round-9) ---------
__global__ __launch_bounds__(256) void gather_kernel(const uint_t* __restrict__ H16,
                                                     const int* __restrict__ off,
                                                     const long long* __restrict__ csr,
                                                     float* __restrict__ out) {
    int tid  = threadIdx.x;
    int wave = tid >> 6;
    int lane = tid & 63;
    int grp  = lane >> 4;
    int il   = lane & 15;
    int wid  = blockIdx.x * 16 + wave * 4 + grp;

    int s = off[wid], e = off[wid + 1];
    float acc[8] = {};

#define ACC8(h, v)                                                            \
    acc[0] += (v) * bf2f((h).x & 0xFFFFu); acc[1] += (v) * bf2f((h).x >> 16); \
    acc[2] += (v) * bf2f((h).y & 0xFFFFu); acc[3] += (v) * bf2f((h).y >> 16); \
    acc[4] += (v) * bf2f((h).z & 0xFFFFu); acc[5] += (v) * bf2f((h).z >> 16); \
    acc[6] += (v) * bf2f((h).w & 0xFFFFu); acc[7] += (v) * bf2f((h).w >> 16);

    int p = s;
    for (; p + 3 < e; p += 4) {
        long long cv0 = __builtin_nontemporal_load(&csr[p]);
        long long cv1 = __builtin_nontemporal_load(&csr[p + 1]);
        long long cv2 = __builtin_nontemporal_load(&csr[p + 2]);
        long long cv3 = __builtin_nontemporal_load(&csr[p + 3]);
        uint4 h0 = *(const uint4*)&H16[(long long)(int)(cv0 & 0x1FFFF) * (DIM / 2) + il * 4];
        uint4 h1 = *(const uint4*)&H16[(long long)(int)(cv1 & 0x1FFFF) * (DIM / 2) + il * 4];
        uint4 h2 = *(const uint4*)&H16[(long long)(int)(cv2 & 0x1FFFF) * (DIM / 2) + il * 4];
        uint4 h3 = *(const uint4*)&H16[(long long)(int)(cv3 & 0x1FFFF) * (DIM / 2) + il * 4];
        float v0 = __int_as_float((int)(cv0 >> 32));
        float v1 = __int_as_float((int)(cv1 >> 32));
        float v2 = __int_as_float((int)(cv2 >> 32));
        float v3 = __int_as_float((int)(cv3 >> 32));
        ACC8(h0, v0) ACC8(h1, v1) ACC8(h2, v2) ACC8(h3, v3)
    }
    for (; p < e; ++p) {
        long long cv = __builtin_nontemporal_load(&csr[p]);
        float v = __int_as_float((int)(cv >> 32));
        uint4 h = *(const uint4*)&H16[(long long)(int)(cv & 0x1FFFF) * (DIM / 2) + il * 4];
        ACC8(h, v)
    }
#undef ACC8

    float* op = &out[(long long)wid * DIM + il * 8];
    f32x4 o0 = {acc[0], acc[1], acc[2], acc[3]};
    f32x4 o1 = {acc[4], acc[5], acc[6], acc[7]};
    __builtin_nontemporal_store(o0, (f32x4*)op);
    __builtin_nontemporal_store(o1, (f32x4*)(op + 4));
}

extern "C" void kernel_launch(void* const* d_in, const int* in_sizes, int n_in,
                              void* d_out, int out_size, void* d_ws, size_t ws_size,
                              hipStream_t stream) {
    const float* x    = (const float*)d_in[0];
    const float* oh   = (const float*)d_in[1];
    const float* W0   = (const float*)d_in[2];
    const float* W1   = (const float*)d_in[3];
    const float* W2   = (const float*)d_in[4];
    const int*   rows = (const int*)d_in[5];
    const int*   cols = (const int*)d_in[6];
    const float* vals = (const float*)d_in[7];
    float* out = (float*)d_out;

    // workspace layout
    char* p = (char*)d_ws;
    size_t oW    = 0;                                   // WsumT bf16: 32 KB (64 KB reserved)
    size_t oH    = oW + 64 * 1024;                      // H bf16: 25.6 MB
    size_t oOff  = oH + (size_t)N_NODES * DIM * 2;      // off: N_NODES+1 (+pad)
    size_t oPs   = oOff + (size_t)(N_NODES + 32) * 4;   // psize: 512 ints
    size_t oSlab = oPs + 4096;                          // slabs: 512*4096*8B = 16.8 MB
    size_t oCsr  = oSlab + (size_t)NBIN * PCAP * 8;     // csr: 12.8 MB

    ushort_t*  WT    = (ushort_t*)(p + oW);
    uint_t*    H16   = (uint_t*)(p + oH);
    int*       off   = (int*)(p + oOff);
    int*       psize = (int*)(p + oPs);
    long long* slab  = (long long*)(p + oSlab);
    long long* csr   = (long long*)(p + oCsr);

    (void)hipMemsetAsync(psize, 0, NBIN * sizeof(int), stream);
    pass1_bin<<<P1_BLOCKS + 64, 256, 0, stream>>>(rows, cols, vals, psize, slab,
                                                  W0, W1, W2, WT);
    pass2_sort<<<NBIN, 256, 0, stream>>>(slab, psize, off, csr);
    gemm_mfma<<<(N_NODES + GROWS - 1) / GROWS, 256, 0, stream>>>(x, oh, WT, H16);
    gather_kernel<<<N_NODES / 16, 256, 0, stream>>>(H16, off, csr, out);
}

// Round 13
// 151.331 us; speedup vs baseline: 1.1216x; 1.0695x over previous
//
#include <hip/hip_runtime.h>
#include <hip/hip_bf16.h>

#define N_NODES 100000
#define N_EDGES 1600000
#define DIM 128

#define NBIN 512          // row partitions
#define RPP  196          // rows per partition (196*511 >= 100000)
#define PCAP 4096         // slab capacity per partition (mean 3125)
#define P1_BLOCKS 512
#define CHUNK (N_EDGES / P1_BLOCKS)   // 3125 edges per pass-1 block
#define GEMM_BLOCKS 1563  // ceil(100000/64)

typedef unsigned int uint_t;
typedef unsigned short ushort_t;
typedef float f32x4 __attribute__((ext_vector_type(4)));
typedef __bf16 bf16x8 __attribute__((ext_vector_type(8)));

// fp32 -> bf16 round-to-nearest-even
__device__ inline uint_t f2bf(float f) {
    uint_t u = __float_as_uint(f);
    return (u + 0x7FFFu + ((u >> 16) & 1u)) >> 16;
}
__device__ inline float bf2f(uint_t lo16) { return __uint_as_float(lo16 << 16); }

// ---------------- k0: WT build (blocks 0..63) + psize zero (block 64) -------------
__global__ __launch_bounds__(256) void wt_init(const float* __restrict__ W0,
                                               const float* __restrict__ W1,
                                               const float* __restrict__ W2,
                                               ushort_t* __restrict__ WT,
                                               int* __restrict__ psize) {
    if (blockIdx.x == 64) {
        int i = threadIdx.x;
        if (i < NBIN / 2) { ((int2*)psize)[i] = make_int2(0, 0); }
        return;
    }
    int i = blockIdx.x * 256 + threadIdx.x;   // < 16384
    int m = i & 127, k = i >> 7;
    float s = W0[k * DIM + m] + W1[k * DIM + m] + W2[k * DIM + m];
    WT[m * DIM + k] = (ushort_t)f2bf(s);      // transposed bf16 (32 KB)
}

// ---------------- k1: fused pass1 (bin) || gemm (MFMA) ----------------------------
// Role-split blocks, 3:1 gemm:pass1 interleave so both roles are co-resident.
// Shared-memory union: pass1 needs 45.7 KB, gemm needs 17.4 KB.
#define GROWS 64
#define XSTR 136   // bf16 per row (128 + 8 pad)

__global__ __launch_bounds__(256) void fused_p1_gemm(
        const int* __restrict__ rows, const int* __restrict__ cols,
        const float* __restrict__ vals, int* __restrict__ psize,
        long long* __restrict__ slab,
        const float* __restrict__ x, const float* __restrict__ oh,
        const ushort_t* __restrict__ WT, uint_t* __restrict__ H16) {
    __shared__ __align__(16) char smem[8192 + CHUNK * 8 + CHUNK * 4];  // 45692 B

    int role, idx;
    if (blockIdx.x < 2048) {
        int g = blockIdx.x >> 2, sb = blockIdx.x & 3;
        if (sb == 3) { role = 1; idx = g; }            // pass1: 512 blocks
        else         { role = 0; idx = g * 3 + sb; }   // gemm: 0..1535
    } else {
        role = 0; idx = 1536 + (int)(blockIdx.x - 2048);  // gemm: 1536..1562
    }
    int t = threadIdx.x;

    if (role == 1) {
        // ---------------- pass1: coarse bin into 512 partition slabs ----------
        int* hist   = (int*)smem;            // 2 KB
        int* binoff = hist + NBIN;           // 2 KB
        int* resv   = binoff + NBIN;         // 2 KB
        int* curs   = resv + NBIN;           // 2 KB
        long long* ebuf = (long long*)(smem + 8192);          // 25 KB
        int* edest  = (int*)(smem + 8192 + CHUNK * 8);        // 12.5 KB

        int e0 = idx * CHUNK;

        for (int i = t; i < NBIN; i += 256) hist[i] = 0;
        __syncthreads();

        for (int i = t; i < CHUNK; i += 256) {
            int r = rows[e0 + i];
            atomicAdd(&hist[r / RPP], 1);
        }
        __syncthreads();

        if (t < 64) {
            int b = t * 8;
            int v[8]; int s = 0;
#pragma unroll
            for (int k = 0; k < 8; ++k) { v[k] = hist[b + k]; s += v[k]; }
            int incl = s;
#pragma unroll
            for (int d = 1; d < 64; d <<= 1) {
                int o = __shfl_up(incl, d, 64);
                if (t >= d) incl += o;
            }
            int run = incl - s;
#pragma unroll
            for (int k = 0; k < 8; ++k) { binoff[b + k] = run; run += v[k]; }
        }
        __syncthreads();

        for (int i = t; i < NBIN; i += 256) {
            int len = hist[i];
            int r = (len > 0) ? atomicAdd(&psize[i], len) : 0;
            resv[i] = i * PCAP + r;
            curs[i] = binoff[i];
        }
        __syncthreads();

        for (int i = t; i < CHUNK; i += 256) {
            int   r = rows[e0 + i];
            int   c = cols[e0 + i];
            float v = vals[e0 + i];
            int b  = r / RPP;
            int lr = r - b * RPP;
            int pos = atomicAdd(&curs[b], 1);
            uint_t key = ((uint_t)lr << 17) | (uint_t)c;
            ebuf[pos]  = ((long long)__float_as_int(v) << 32) | (long long)key;
            edest[pos] = resv[b] + (pos - binoff[b]);
        }
        __syncthreads();

        for (int i = t; i < CHUNK; i += 256)
            slab[edest[i]] = ebuf[i];
    } else {
        // ---------------- gemm: LDS-staged coalesced MFMA ---------------------
        ushort_t* xs = (ushort_t*)smem;      // 17408 B

        int wv = t >> 6, l = t & 63;
        int lr = l & 15, kg = l >> 4;
        int lrow = wv * 16 + lr;
        long long base_row = (long long)idx * GROWS;
        long long hr = base_row + lrow;

        const f32x4* xg = (const f32x4*)x;
#pragma unroll
        for (int i = 0; i < 8; ++i) {
            int g = t + i * 256;
            int row = g >> 5, c4 = g & 31;
            long long sr = base_row + row; if (sr >= N_NODES) sr = N_NODES - 1;
            f32x4 v = __builtin_nontemporal_load(xg + sr * 32 + c4);
            ushort_t* d = &xs[row * XSTR + c4 * 4];
            d[0] = (ushort_t)f2bf(v.x); d[1] = (ushort_t)f2bf(v.y);
            d[2] = (ushort_t)f2bf(v.z); d[3] = (ushort_t)f2bf(v.w);
        }
        __syncthreads();

        f32x4 acc[8] = {};
#pragma unroll
        for (int s = 0; s < 4; ++s) {
            bf16x8 b = *(const bf16x8*)&xs[lrow * XSTR + s * 32 + kg * 8];
#pragma unroll
            for (int mt = 0; mt < 8; ++mt) {
                bf16x8 a = *(const bf16x8*)&WT[(mt * 16 + lr) * DIM + s * 32 + kg * 8];
                acc[mt] = __builtin_amdgcn_mfma_f32_16x16x32_bf16(a, b, acc[mt], 0, 0, 0);
            }
        }
        __syncthreads();

        const f32x4* og = (const f32x4*)oh;
#pragma unroll
        for (int i = 0; i < 8; ++i) {
            int g = t + i * 256;
            int row = g >> 5, c4 = g & 31;
            long long sr = base_row + row; if (sr >= N_NODES) sr = N_NODES - 1;
            f32x4 v = __builtin_nontemporal_load(og + sr * 32 + c4);
            ushort_t* d = &xs[row * XSTR + c4 * 4];
            d[0] = (ushort_t)f2bf(v.x); d[1] = (ushort_t)f2bf(v.y);
            d[2] = (ushort_t)f2bf(v.z); d[3] = (ushort_t)f2bf(v.w);
        }
        __syncthreads();

        if (hr < N_NODES) {
#pragma unroll
            for (int mt = 0; mt < 8; ++mt) {
                int c0 = mt * 16 + kg * 4;
                const uint_t* ow = (const uint_t*)&xs[lrow * XSTR + c0];
                uint_t w0 = ow[0], w1 = ow[1];
                float f0 = acc[mt].x + bf2f(w0 & 0xFFFFu);
                float f1 = acc[mt].y + bf2f(w0 >> 16);
                float f2 = acc[mt].z + bf2f(w1 & 0xFFFFu);
                float f3 = acc[mt].w + bf2f(w1 >> 16);
                uint2 pk;
                pk.x = f2bf(f0) | (f2bf(f1) << 16);
                pk.y = f2bf(f2) | (f2bf(f3) << 16);
                *(uint2*)&H16[(size_t)hr * (DIM / 2) + c0 / 2] = pk;
            }
        }
    }
}

// ---------------- Pass 2: per-partition LDS counting sort (round-12) --------------
__global__ __launch_bounds__(256) void pass2_sort(
        const long long* __restrict__ slab, const int* __restrict__ psize,
        int* __restrict__ off, long long* __restrict__ csr) {
    __shared__ int pb[NBIN + 1];
    __shared__ int cnt[RPP + 1];
    __shared__ int loff[RPP + 1];
    __shared__ int curs[RPP];
    __shared__ long long ebuf[PCAP];   // 32 KB

    int p = blockIdx.x, t = threadIdx.x;

    if (t < 64) {
        int b = t * 8;
        int v[8]; int s = 0;
#pragma unroll
        for (int k = 0; k < 8; ++k) { v[k] = min(psize[b + k], PCAP); s += v[k]; }
        int incl = s;
#pragma unroll
        for (int d = 1; d < 64; d <<= 1) {
            int o = __shfl_up(incl, d, 64);
            if (t >= d) incl += o;
        }
        int run = incl - s;
#pragma unroll
        for (int k = 0; k < 8; ++k) { pb[b + k] = run; run += v[k]; }
        if (t == 63) pb[NBIN] = incl;
    }
    for (int i = t; i < RPP + 1; i += 256) cnt[i] = 0;
    __syncthreads();

    int n = min(psize[p], PCAP);
    int base = pb[p];
    int rlo = p * RPP;
    int nrows = N_NODES - rlo;
    if (nrows > RPP) nrows = RPP;
    if (nrows < 0) nrows = 0;
    const long long* seg = slab + (long long)p * PCAP;

    if (p == NBIN - 1 && t == 0) off[N_NODES] = pb[NBIN];

    for (int i = t; i < n; i += 256) {
        long long ev = __builtin_nontemporal_load(&seg[i]);
        ebuf[i] = ev;
        uint_t key = (uint_t)(ev & 0xFFFFFFFFll);
        atomicAdd(&cnt[key >> 17], 1);
    }
    __syncthreads();

    if (t < 64) {
        int b4 = t * 4;
        int v[4]; int s = 0;
#pragma unroll
        for (int k = 0; k < 4; ++k) {
            int idx = b4 + k;
            v[k] = (idx < RPP) ? cnt[idx] : 0;
            s += v[k];
        }
        int incl = s;
#pragma unroll
        for (int d = 1; d < 64; d <<= 1) {
            int o = __shfl_up(incl, d, 64);
            if (t >= d) incl += o;
        }
        int run = incl - s;
#pragma unroll
        for (int k = 0; k < 4; ++k) {
            int idx = b4 + k;
            if (idx < RPP) loff[idx] = run;
            run += v[k];
        }
    }
    __syncthreads();

    for (int i = t; i < nrows; i += 256) {
        curs[i] = loff[i];
        off[rlo + i] = base + loff[i];
    }
    __syncthreads();

    for (int i = t; i < n; i += 256) {
        long long ev = ebuf[i];
        uint_t key = (uint_t)(ev & 0xFFFFFFFFll);
        int lr = key >> 17;
        uint_t c = key & 0x1FFFFu;
        int pos = atomicAdd(&curs[lr], 1);
        csr[base + pos] = (long long)(((unsigned long long)ev & 0xFFFFFFFF00000000ull) | c);
    }
}

// ---------------- Gather: 4 rows/wave, 16 lanes/row, 4-deep MLP (round-9) ---------
__global__ __launch_bounds__(256) void gather_kernel(const uint_t* __restrict__ H16,
                                                     const int* __restrict__ off,
                                                     const long long* __restrict__ csr,
                                                     float* __restrict__ out) {
    int tid  = threadIdx.x;
    int wave = tid >> 6;
    int lane = tid & 63;
    int grp  = lane >> 4;
    int il   = lane & 15;
    int wid  = blockIdx.x * 16 + wave * 4 + grp;

    int s = off[wid], e = off[wid + 1];
    float acc[8] = {};

#define ACC8(h, v)                                                            \
    acc[0] += (v) * bf2f((h).x & 0xFFFFu); acc[1] += (v) * bf2f((h).x >> 16); \
    acc[2] += (v) * bf2f((h).y & 0xFFFFu); acc[3] += (v) * bf2f((h).y >> 16); \
    acc[4] += (v) * bf2f((h).z & 0xFFFFu); acc[5] += (v) * bf2f((h).z >> 16); \
    acc[6] += (v) * bf2f((h).w & 0xFFFFu); acc[7] += (v) * bf2f((h).w >> 16);

    int p = s;
    for (; p + 3 < e; p += 4) {
        long long cv0 = __builtin_nontemporal_load(&csr[p]);
        long long cv1 = __builtin_nontemporal_load(&csr[p + 1]);
        long long cv2 = __builtin_nontemporal_load(&csr[p + 2]);
        long long cv3 = __builtin_nontemporal_load(&csr[p + 3]);
        uint4 h0 = *(const uint4*)&H16[(long long)(int)(cv0 & 0x1FFFF) * (DIM / 2) + il * 4];
        uint4 h1 = *(const uint4*)&H16[(long long)(int)(cv1 & 0x1FFFF) * (DIM / 2) + il * 4];
        uint4 h2 = *(const uint4*)&H16[(long long)(int)(cv2 & 0x1FFFF) * (DIM / 2) + il * 4];
        uint4 h3 = *(const uint4*)&H16[(long long)(int)(cv3 & 0x1FFFF) * (DIM / 2) + il * 4];
        float v0 = __int_as_float((int)(cv0 >> 32));
        float v1 = __int_as_float((int)(cv1 >> 32));
        float v2 = __int_as_float((int)(cv2 >> 32));
        float v3 = __int_as_float((int)(cv3 >> 32));
        ACC8(h0, v0) ACC8(h1, v1) ACC8(h2, v2) ACC8(h3, v3)
    }
    for (; p < e; ++p) {
        long long cv = __builtin_nontemporal_load(&csr[p]);
        float v = __int_as_float((int)(cv >> 32));
        uint4 h = *(const uint4*)&H16[(long long)(int)(cv & 0x1FFFF) * (DIM / 2) + il * 4];
        ACC8(h, v)
    }
#undef ACC8

    float* op = &out[(long long)wid * DIM + il * 8];
    f32x4 o0 = {acc[0], acc[1], acc[2], acc[3]};
    f32x4 o1 = {acc[4], acc[5], acc[6], acc[7]};
    __builtin_nontemporal_store(o0, (f32x4*)op);
    __builtin_nontemporal_store(o1, (f32x4*)(op + 4));
}

extern "C" void kernel_launch(void* const* d_in, const int* in_sizes, int n_in,
                              void* d_out, int out_size, void* d_ws, size_t ws_size,
                              hipStream_t stream) {
    const float* x    = (const float*)d_in[0];
    const float* oh   = (const float*)d_in[1];
    const float* W0   = (const float*)d_in[2];
    const float* W1   = (const float*)d_in[3];
    const float* W2   = (const float*)d_in[4];
    const int*   rows = (const int*)d_in[5];
    const int*   cols = (const int*)d_in[6];
    const float* vals = (const float*)d_in[7];
    float* out = (float*)d_out;

    // workspace layout
    char* p = (char*)d_ws;
    size_t oW    = 0;                                   // WsumT bf16: 32 KB (64 KB reserved)
    size_t oH    = oW + 64 * 1024;                      // H bf16: 25.6 MB
    size_t oOff  = oH + (size_t)N_NODES * DIM * 2;      // off: N_NODES+1 (+pad)
    size_t oPs   = oOff + (size_t)(N_NODES + 32) * 4;   // psize: 512 ints
    size_t oSlab = oPs + 4096;                          // slabs: 512*4096*8B = 16.8 MB
    size_t oCsr  = oSlab + (size_t)NBIN * PCAP * 8;     // csr: 12.8 MB

    ushort_t*  WT    = (ushort_t*)(p + oW);
    uint_t*    H16   = (uint_t*)(p + oH);
    int*       off   = (int*)(p + oOff);
    int*       psize = (int*)(p + oPs);
    long long* slab  = (long long*)(p + oSlab);
    long long* csr   = (long long*)(p + oCsr);

    wt_init<<<65, 256, 0, stream>>>(W0, W1, W2, WT, psize);
    fused_p1_gemm<<<2075, 256, 0, stream>>>(rows, cols, vals, psize, slab,
                                            x, oh, WT, H16);
    pass2_sort<<<NBIN, 256, 0, stream>>>(slab, psize, off, csr);
    gather_kernel<<<N_NODES / 16, 256, 0, stream>>>(H16, off, csr, out);
}